// Round 1
// baseline (1256.118 us; speedup 1.0000x reference)
//
#include <hip/hip_runtime.h>
#include <hip/hip_bf16.h>

#define NEG_SLOPE 0.2f

// ---------- helpers: monotone float<->uint encoding for atomicMax ----------
__device__ __forceinline__ unsigned fenc(float f) {
    unsigned u = __float_as_uint(f);
    return (u & 0x80000000u) ? ~u : (u | 0x80000000u);
}
__device__ __forceinline__ float fdec(unsigned e) {
    unsigned u = (e & 0x80000000u) ? (e & 0x7fffffffu) : ~e;
    return __uint_as_float(u);
}

// ---------- GEMM: H = f(X) @ W, plus AS = H@a_src, AD = H@a_dst ----------
// f(X) = relu(X + bias_in) if RELU_BIAS else X.
// One wave per row; lane = output column (M <= 64). W staged in LDS.
template <int K, int M, bool RELU_BIAS>
__global__ __launch_bounds__(256) void gemm_alpha(
    const float* __restrict__ X, const float* __restrict__ W,
    const float* __restrict__ a_s, const float* __restrict__ a_d,
    const float* __restrict__ bias_in,
    float* __restrict__ H, float* __restrict__ AS, float* __restrict__ AD,
    int N)
{
    __shared__ float Wlds[K * M];
    __shared__ float Xbuf[4][K];

    for (int i = threadIdx.x; i < K * M; i += 256) Wlds[i] = W[i];
    __syncthreads();

    const int wave = threadIdx.x >> 6;
    const int lane = threadIdx.x & 63;
    const float asv = (lane < M) ? a_s[lane] : 0.0f;
    const float adv = (lane < M) ? a_d[lane] : 0.0f;

    const int rows_per_step = gridDim.x * 4;
    for (int r0 = blockIdx.x * 4; r0 < N; r0 += rows_per_step) {
        const int r = r0 + wave;  // N % 4 == 0, so r < N
        // stage row r (with optional input bias+relu)
        const float* xr = X + (long)r * K;
        #pragma unroll
        for (int j = lane; j < K; j += 64) {
            float v = xr[j];
            if (RELU_BIAS) { v += bias_in[j]; v = v > 0.0f ? v : 0.0f; }
            Xbuf[wave][j] = v;
        }
        __syncthreads();

        float acc = 0.0f;
        if (lane < M) {
            const float4* xb4 = (const float4*)Xbuf[wave];
            #pragma unroll 4
            for (int k4 = 0; k4 < K / 4; ++k4) {
                float4 xv = xb4[k4];
                acc = fmaf(xv.x, Wlds[(k4 * 4 + 0) * M + lane], acc);
                acc = fmaf(xv.y, Wlds[(k4 * 4 + 1) * M + lane], acc);
                acc = fmaf(xv.z, Wlds[(k4 * 4 + 2) * M + lane], acc);
                acc = fmaf(xv.w, Wlds[(k4 * 4 + 3) * M + lane], acc);
            }
            H[(long)r * M + lane] = acc;
        }
        // alpha reductions (lanes >= M contribute 0)
        float vs = acc * asv, vd = acc * adv;
        #pragma unroll
        for (int o = 32; o >= 1; o >>= 1) {
            vs += __shfl_xor(vs, o);
            vd += __shfl_xor(vd, o);
        }
        if (lane == 0) { AS[r] = vs; AD[r] = vd; }
        __syncthreads();  // protect Xbuf WAR for next iteration
    }
}

// ---------- edge pass A: segment max of leaky_relu(as[src]+ad[dst]) ----------
__global__ __launch_bounds__(256) void edge_max_k(
    const int* __restrict__ esrc, const int* __restrict__ edst, int E, int Etot,
    const float* __restrict__ as_, const float* __restrict__ ad_,
    unsigned* __restrict__ menc)
{
    int i = blockIdx.x * 256 + threadIdx.x;
    if (i >= Etot) return;
    int s = (i < E) ? esrc[i] : (i - E);
    int d = (i < E) ? edst[i] : (i - E);
    float e = as_[s] + ad_[d];
    e = e > 0.0f ? e : NEG_SLOPE * e;
    atomicMax(menc + d, fenc(e));
}

// ---------- edge pass B: denom[dst] += exp(e - m[dst]) ----------
__global__ __launch_bounds__(256) void edge_den_k(
    const int* __restrict__ esrc, const int* __restrict__ edst, int E, int Etot,
    const float* __restrict__ as_, const float* __restrict__ ad_,
    const unsigned* __restrict__ menc, float* __restrict__ den)
{
    int i = blockIdx.x * 256 + threadIdx.x;
    if (i >= Etot) return;
    int s = (i < E) ? esrc[i] : (i - E);
    int d = (i < E) ? edst[i] : (i - E);
    float e = as_[s] + ad_[d];
    e = e > 0.0f ? e : NEG_SLOPE * e;
    float ex = __expf(e - fdec(menc[d]));
    atomicAdd(den + d, ex);
}

// ---------- edge pass C: OUT[dst] += attn * H[src], M lanes per edge ----------
template <int M>
__global__ __launch_bounds__(256) void edge_agg_k(
    const int* __restrict__ esrc, const int* __restrict__ edst, int E, int Etot,
    const float* __restrict__ as_, const float* __restrict__ ad_,
    const unsigned* __restrict__ menc, const float* __restrict__ den,
    const float* __restrict__ H, float* __restrict__ OUT)
{
    int t = blockIdx.x * 256 + threadIdx.x;
    int i = t / M;
    int f = t % M;
    if (i >= Etot) return;
    int s = (i < E) ? esrc[i] : (i - E);
    int d = (i < E) ? edst[i] : (i - E);
    float e = as_[s] + ad_[d];
    e = e > 0.0f ? e : NEG_SLOPE * e;
    float w = __expf(e - fdec(menc[d])) / den[d];
    atomicAdd(OUT + (long)d * M + f, H[(long)s * M + f] * w);
}

// ---------- final FC: out[n] = relu(H2[n]+b2) . Wfc + bfc ----------
__global__ __launch_bounds__(256) void fc_out_k(
    const float* __restrict__ H2, const float* __restrict__ b2,
    const float* __restrict__ Wfc, const float* __restrict__ bfc,
    float* __restrict__ out, int N)
{
    int t = blockIdx.x * 256 + threadIdx.x;
    int n = t >> 5;
    int f = t & 31;
    if (n >= N) return;
    float v = H2[(long)n * 32 + f] + b2[f];
    v = v > 0.0f ? v : 0.0f;
    v *= Wfc[f];
    #pragma unroll
    for (int o = 16; o >= 1; o >>= 1) v += __shfl_xor(v, o, 32);
    if (f == 0) out[n] = v + bfc[0];
}

extern "C" void kernel_launch(void* const* d_in, const int* in_sizes, int n_in,
                              void* d_out, int out_size, void* d_ws, size_t ws_size,
                              hipStream_t stream) {
    const float* x      = (const float*)d_in[0];
    const int*   eidx   = (const int*)d_in[1];
    const float* W1     = (const float*)d_in[2];
    const float* a_src1 = (const float*)d_in[3];
    const float* a_dst1 = (const float*)d_in[4];
    const float* b1     = (const float*)d_in[5];
    const float* W2     = (const float*)d_in[6];
    const float* a_src2 = (const float*)d_in[7];
    const float* a_dst2 = (const float*)d_in[8];
    const float* b2     = (const float*)d_in[9];
    const float* Wfc    = (const float*)d_in[10];
    const float* bfc    = (const float*)d_in[11];
    float* out = (float*)d_out;

    const int N = in_sizes[0] / 256;       // 100000
    const int E = in_sizes[1] / 2;         // 1600000
    const int Etot = E + N;                // 1700000
    const int* esrc = eidx;
    const int* edst = eidx + E;

    // workspace layout (floats)
    float* ws = (float*)d_ws;
    unsigned* m1 = (unsigned*)(ws + 0);        // N
    float* den1  = ws + N;                     // N
    unsigned* m2 = (unsigned*)(ws + 2 * N);    // N
    float* den2  = ws + 3 * N;                 // N
    float* h1out = ws + 4 * N;                 // N*64
    float* h2out = h1out + (long)N * 64;       // N*32
    // ---- zeroed region ends here ----
    float* h1    = h2out + (long)N * 32;       // N*64
    float* h2    = h1 + (long)N * 64;          // N*32
    float* as1   = h2 + (long)N * 32;          // N
    float* ad1   = as1 + N;
    float* as2   = ad1 + N;
    float* ad2   = as2 + N;

    size_t zero_bytes = (size_t)(4 * N + (long)N * 64 + (long)N * 32) * 4;
    hipMemsetAsync(d_ws, 0, zero_bytes, stream);

    // ---- layer 1 ----
    gemm_alpha<256, 64, false><<<1024, 256, 0, stream>>>(
        x, W1, a_src1, a_dst1, nullptr, h1, as1, ad1, N);
    {
        int blocks = (Etot + 255) / 256;
        edge_max_k<<<blocks, 256, 0, stream>>>(esrc, edst, E, Etot, as1, ad1, m1);
        edge_den_k<<<blocks, 256, 0, stream>>>(esrc, edst, E, Etot, as1, ad1, m1, den1);
        int blocksC = (int)(((long)Etot * 64 + 255) / 256);
        edge_agg_k<64><<<blocksC, 256, 0, stream>>>(esrc, edst, E, Etot, as1, ad1, m1, den1, h1, h1out);
    }

    // ---- layer 2 (fuses bias1 + relu into input load) ----
    gemm_alpha<64, 32, true><<<1024, 256, 0, stream>>>(
        h1out, W2, a_src2, a_dst2, b1, h2, as2, ad2, N);
    {
        int blocks = (Etot + 255) / 256;
        edge_max_k<<<blocks, 256, 0, stream>>>(esrc, edst, E, Etot, as2, ad2, m2);
        edge_den_k<<<blocks, 256, 0, stream>>>(esrc, edst, E, Etot, as2, ad2, m2, den2);
        int blocksC = (int)(((long)Etot * 32 + 255) / 256);
        edge_agg_k<32><<<blocksC, 256, 0, stream>>>(esrc, edst, E, Etot, as2, ad2, m2, den2, h2, h2out);
    }

    // ---- final FC (fuses bias2 + relu) ----
    {
        int blocks = (int)(((long)N * 32 + 255) / 256);
        fc_out_k<<<blocks, 256, 0, stream>>>(h2out, b2, Wfc, bfc, out, N);
    }
}

// Round 2
// 959.687 us; speedup vs baseline: 1.3089x; 1.3089x over previous
//
#include <hip/hip_runtime.h>
#include <hip/hip_bf16.h>

#define NEG_SLOPE 0.2f
#define NINF (-1e30f)

// ================= CSR build (graph shared by both layers) =================

__global__ __launch_bounds__(256) void hist_k(
    const int* __restrict__ edst, int E, int Etot, int* __restrict__ cnt)
{
    int i = blockIdx.x * 256 + threadIdx.x;
    if (i >= Etot) return;
    int d = (i < E) ? edst[i] : (i - E);
    atomicAdd(cnt + d, 1);
}

// single-block exclusive scan of cnt[0..N) -> rowptr (in place) + woff copy
__global__ __launch_bounds__(1024) void scan_k(
    int* __restrict__ cnt /* aliases rowptr */, int* __restrict__ woff,
    int N, int Etot)
{
    __shared__ int part[1024];
    const int t = threadIdx.x;
    const int seg = (N + 1023) / 1024;
    const int lo = t * seg, hi = min(lo + seg, N);
    int sum = 0;
    for (int i = lo; i < hi; ++i) sum += cnt[i];
    part[t] = sum;
    __syncthreads();
    for (int o = 1; o < 1024; o <<= 1) {
        int v = (t >= o) ? part[t - o] : 0;
        __syncthreads();
        part[t] += v;
        __syncthreads();
    }
    int run = part[t] - sum;  // exclusive prefix
    for (int i = lo; i < hi; ++i) {
        int c = cnt[i];
        cnt[i] = run;   // rowptr[i]
        woff[i] = run;
        run += c;
    }
    if (t == 1023) cnt[N] = Etot;
}

__global__ __launch_bounds__(256) void scatter_k(
    const int* __restrict__ esrc, const int* __restrict__ edst, int E, int Etot,
    int* __restrict__ woff, int* __restrict__ csr_src)
{
    int i = blockIdx.x * 256 + threadIdx.x;
    if (i >= Etot) return;
    int d = (i < E) ? edst[i] : (i - E);
    int s = (i < E) ? esrc[i] : (i - E);
    int pos = atomicAdd(woff + d, 1);
    csr_src[pos] = s;
}

// ========== GEMM: H = f(X) @ W, plus AS = H@a_src, AD = H@a_dst ==========
template <int K, int M, bool RELU_BIAS>
__global__ __launch_bounds__(256) void gemm_alpha(
    const float* __restrict__ X, const float* __restrict__ W,
    const float* __restrict__ a_s, const float* __restrict__ a_d,
    const float* __restrict__ bias_in,
    float* __restrict__ H, float* __restrict__ AS, float* __restrict__ AD,
    int N)
{
    __shared__ float Wlds[K * M];
    __shared__ float Xbuf[4][K];

    for (int i = threadIdx.x; i < K * M; i += 256) Wlds[i] = W[i];
    __syncthreads();

    const int wave = threadIdx.x >> 6;
    const int lane = threadIdx.x & 63;
    const float asv = (lane < M) ? a_s[lane] : 0.0f;
    const float adv = (lane < M) ? a_d[lane] : 0.0f;

    const int rows_per_step = gridDim.x * 4;
    for (int r0 = blockIdx.x * 4; r0 < N; r0 += rows_per_step) {
        const int r = r0 + wave;  // N % 4 == 0
        const float* xr = X + (long)r * K;
        #pragma unroll
        for (int j = lane; j < K; j += 64) {
            float v = xr[j];
            if (RELU_BIAS) { v += bias_in[j]; v = v > 0.0f ? v : 0.0f; }
            Xbuf[wave][j] = v;
        }
        __syncthreads();

        float acc = 0.0f;
        if (lane < M) {
            const float4* xb4 = (const float4*)Xbuf[wave];
            #pragma unroll 4
            for (int k4 = 0; k4 < K / 4; ++k4) {
                float4 xv = xb4[k4];
                acc = fmaf(xv.x, Wlds[(k4 * 4 + 0) * M + lane], acc);
                acc = fmaf(xv.y, Wlds[(k4 * 4 + 1) * M + lane], acc);
                acc = fmaf(xv.z, Wlds[(k4 * 4 + 2) * M + lane], acc);
                acc = fmaf(xv.w, Wlds[(k4 * 4 + 3) * M + lane], acc);
            }
            H[(long)r * M + lane] = acc;
        }
        float vs = acc * asv, vd = acc * adv;
        #pragma unroll
        for (int o = 32; o >= 1; o >>= 1) {
            vs += __shfl_xor(vs, o);
            vd += __shfl_xor(vd, o);
        }
        if (lane == 0) { AS[r] = vs; AD[r] = vd; }
        __syncthreads();
    }
}

// ===== fused softmax + aggregation over CSR: one wave per dst node =====
// online softmax (flash-style) so arbitrary degree works in one pass
template <int M>  // feature width: 64 (layer1) or 32 (layer2)
__global__ __launch_bounds__(256) void agg_csr_k(
    const int* __restrict__ rowptr, const int* __restrict__ csr_src,
    const float* __restrict__ as_, const float* __restrict__ ad_,
    const float* __restrict__ H, float* __restrict__ OUT, int N)
{
    __shared__ float lw[4][64];
    __shared__ int   ls[4][64];
    const int wave = threadIdx.x >> 6;
    const int lane = threadIdx.x & 63;
    const int d = blockIdx.x * 4 + wave;
    if (d >= N) return;
    const int r0 = rowptr[d];
    const int deg = rowptr[d + 1] - r0;
    const float adv = ad_[d];

    const int f  = lane & (M - 1);
    const int eh = (M == 64) ? 0 : (lane >> 5);  // which edge of the pair

    float m = NINF, den = 0.0f, acc = 0.0f;
    for (int base = 0; base < deg; base += 64) {
        int j = base + lane;
        int s = 0;
        float e = NINF;
        if (j < deg) {
            s = csr_src[r0 + j];
            e = as_[s] + adv;
            e = e > 0.0f ? e : NEG_SLOPE * e;
        }
        // wave max of chunk
        float cm = e;
        #pragma unroll
        for (int o = 32; o; o >>= 1) cm = fmaxf(cm, __shfl_xor(cm, o));
        if (cm > m) {
            float sc = __expf(m - cm);  // m=-inf -> 0, zeroes stale acc/den
            acc *= sc; den *= sc; m = cm;
        }
        float w = __expf(e - m);  // e=-inf -> 0
        float ws = w;
        #pragma unroll
        for (int o = 32; o; o >>= 1) ws += __shfl_xor(ws, o);
        den += ws;
        lw[wave][lane] = w;
        ls[wave][lane] = s;
        // wave-synchronous: same wave wrote, same wave reads (lgkmcnt ordered)
        int cnt = min(64, deg - base);
        if (M == 64) {
            #pragma unroll 4
            for (int jj = 0; jj < cnt; ++jj) {
                float wj = lw[wave][jj];
                int   sj = ls[wave][jj];
                acc = fmaf(wj, H[(long)sj * 64 + lane], acc);
            }
        } else {
            #pragma unroll 4
            for (int jj = 0; jj < cnt; jj += 2) {
                int je = jj + eh;
                float wj = (je < cnt) ? lw[wave][je] : 0.0f;
                int   sj = (je < cnt) ? ls[wave][je] : 0;
                acc = fmaf(wj, H[(long)sj * 32 + f], acc);
            }
        }
    }
    if (M == 32) acc += __shfl_xor(acc, 32);
    float r = acc / den;
    if (M == 64) OUT[(long)d * 64 + lane] = r;
    else if (lane < 32) OUT[(long)d * 32 + lane] = r;
}

// ---------- final FC: out[n] = relu(H2[n]+b2) . Wfc + bfc ----------
__global__ __launch_bounds__(256) void fc_out_k(
    const float* __restrict__ H2, const float* __restrict__ b2,
    const float* __restrict__ Wfc, const float* __restrict__ bfc,
    float* __restrict__ out, int N)
{
    int t = blockIdx.x * 256 + threadIdx.x;
    int n = t >> 5;
    int fidx = t & 31;
    if (n >= N) return;
    float v = H2[(long)n * 32 + fidx] + b2[fidx];
    v = v > 0.0f ? v : 0.0f;
    v *= Wfc[fidx];
    #pragma unroll
    for (int o = 16; o >= 1; o >>= 1) v += __shfl_xor(v, o, 32);
    if (fidx == 0) out[n] = v + bfc[0];
}

extern "C" void kernel_launch(void* const* d_in, const int* in_sizes, int n_in,
                              void* d_out, int out_size, void* d_ws, size_t ws_size,
                              hipStream_t stream) {
    const float* x      = (const float*)d_in[0];
    const int*   eidx   = (const int*)d_in[1];
    const float* W1     = (const float*)d_in[2];
    const float* a_src1 = (const float*)d_in[3];
    const float* a_dst1 = (const float*)d_in[4];
    const float* b1     = (const float*)d_in[5];
    const float* W2     = (const float*)d_in[6];
    const float* a_src2 = (const float*)d_in[7];
    const float* a_dst2 = (const float*)d_in[8];
    const float* b2     = (const float*)d_in[9];
    const float* Wfc    = (const float*)d_in[10];
    const float* bfc    = (const float*)d_in[11];
    float* out = (float*)d_out;

    const int N = in_sizes[0] / 256;       // 100000
    const int E = in_sizes[1] / 2;         // 1600000
    const int Etot = E + N;                // 1700000
    const int* esrc = eidx;
    const int* edst = eidx + E;

    // ---- workspace layout (4B units) ----
    int* rowptr = (int*)d_ws;                        // N+1 (also hist counters)
    int* woff   = rowptr + (N + 1);                  // N
    int* csr    = woff + N;                          // Etot
    float* as1  = (float*)(csr + Etot);              // N
    float* ad1  = as1 + N;                           // N
    float* as2  = ad1 + N;                           // N
    float* ad2  = as2 + N;                           // N
    float* A    = ad2 + N;                           // 64N  (h1; later h2 | h2out)
    float* B    = A + (long)N * 64;                  // 64N  (h1out)
    float* h1    = A;
    float* h1out = B;
    float* h2    = A;                                // reuse: h1 dead after agg1
    float* h2out = A + (long)N * 32;

    // zero only the histogram counters
    hipMemsetAsync(rowptr, 0, (size_t)(N + 1) * 4, stream);

    // ---- CSR build (once, shared by both layers) ----
    {
        int blocks = (Etot + 255) / 256;
        hist_k<<<blocks, 256, 0, stream>>>(edst, E, Etot, rowptr);
        scan_k<<<1, 1024, 0, stream>>>(rowptr, woff, N, Etot);
        scatter_k<<<blocks, 256, 0, stream>>>(esrc, edst, E, Etot, woff, csr);
    }

    const int aggBlocks = (N + 3) / 4;

    // ---- layer 1 ----
    gemm_alpha<256, 64, false><<<1024, 256, 0, stream>>>(
        x, W1, a_src1, a_dst1, nullptr, h1, as1, ad1, N);
    agg_csr_k<64><<<aggBlocks, 256, 0, stream>>>(
        rowptr, csr, as1, ad1, h1, h1out, N);

    // ---- layer 2 (fuses bias1 + relu into input load) ----
    gemm_alpha<64, 32, true><<<1024, 256, 0, stream>>>(
        h1out, W2, a_src2, a_dst2, b1, h2, as2, ad2, N);
    agg_csr_k<32><<<aggBlocks, 256, 0, stream>>>(
        rowptr, csr, as2, ad2, h2, h2out, N);

    // ---- final FC (fuses bias2 + relu) ----
    {
        int blocks = (int)(((long)N * 32 + 255) / 256);
        fc_out_k<<<blocks, 256, 0, stream>>>(h2out, b2, Wfc, bfc, out, N);
    }
}

// Round 3
// 725.130 us; speedup vs baseline: 1.7323x; 1.3235x over previous
//
#include <hip/hip_runtime.h>
#include <hip/hip_bf16.h>

#define NEG_SLOPE 0.2f
#define NINF (-1e30f)

// ================= CSR build (graph shared by both layers) =================

__global__ __launch_bounds__(256) void hist_k(
    const int* __restrict__ edst, int E, int Etot, int* __restrict__ cnt)
{
    int i = blockIdx.x * 256 + threadIdx.x;
    if (i >= Etot) return;
    int d = (i < E) ? edst[i] : (i - E);
    atomicAdd(cnt + d, 1);
}

// ---- multi-block scan: B (partial sums) -> C (scan partials) -> D (final) ----
// each block covers 1024 elements (4 per thread)

__global__ __launch_bounds__(256) void scan_partial_k(
    const int* __restrict__ cnt, int N, int* __restrict__ partials)
{
    __shared__ int red[256];
    const int t = threadIdx.x;
    const int base = blockIdx.x * 1024 + t * 4;
    int sum = 0;
    #pragma unroll
    for (int k = 0; k < 4; ++k) {
        int i = base + k;
        if (i < N) sum += cnt[i];
    }
    red[t] = sum;
    __syncthreads();
    #pragma unroll
    for (int o = 128; o; o >>= 1) {
        if (t < o) red[t] += red[t + o];
        __syncthreads();
    }
    if (t == 0) partials[blockIdx.x] = red[0];
}

__global__ __launch_bounds__(128) void scan_partials_scan_k(
    int* __restrict__ partials, int nb)
{
    __shared__ int sh[128];
    const int t = threadIdx.x;
    int v = (t < nb) ? partials[t] : 0;
    sh[t] = v;
    __syncthreads();
    #pragma unroll
    for (int o = 1; o < 128; o <<= 1) {
        int u = (t >= o) ? sh[t - o] : 0;
        __syncthreads();
        sh[t] += u;
        __syncthreads();
    }
    if (t < nb) partials[t] = sh[t] - v;  // exclusive
}

__global__ __launch_bounds__(256) void scan_final_k(
    int* __restrict__ cnt /* in: counts, out: rowptr */,
    int* __restrict__ woff, const int* __restrict__ partials, int N, int Etot)
{
    __shared__ int sh[256];
    const int t = threadIdx.x;
    const int base = blockIdx.x * 1024 + t * 4;
    int v[4];
    int sum = 0;
    #pragma unroll
    for (int k = 0; k < 4; ++k) {
        int i = base + k;
        v[k] = (i < N) ? cnt[i] : 0;
        sum += v[k];
    }
    sh[t] = sum;
    __syncthreads();
    #pragma unroll
    for (int o = 1; o < 256; o <<= 1) {
        int u = (t >= o) ? sh[t - o] : 0;
        __syncthreads();
        sh[t] += u;
        __syncthreads();
    }
    int run = sh[t] - sum + partials[blockIdx.x];
    #pragma unroll
    for (int k = 0; k < 4; ++k) {
        int i = base + k;
        if (i < N) { cnt[i] = run; woff[i] = run; }
        run += v[k];
    }
    if (blockIdx.x == 0 && t == 0) cnt[N] = Etot;
}

__global__ __launch_bounds__(256) void scatter_k(
    const int* __restrict__ esrc, const int* __restrict__ edst, int E, int Etot,
    int* __restrict__ woff, int* __restrict__ csr_src)
{
    int i = blockIdx.x * 256 + threadIdx.x;
    if (i >= Etot) return;
    int d = (i < E) ? edst[i] : (i - E);
    int s = (i < E) ? esrc[i] : (i - E);
    int pos = atomicAdd(woff + d, 1);
    csr_src[pos] = s;
}

// ========== GEMM: H = f(X) @ W, plus AS = H@a_src, AD = H@a_dst ==========
template <int K, int M, bool RELU_BIAS>
__global__ __launch_bounds__(256) void gemm_alpha(
    const float* __restrict__ X, const float* __restrict__ W,
    const float* __restrict__ a_s, const float* __restrict__ a_d,
    const float* __restrict__ bias_in,
    float* __restrict__ H, float* __restrict__ AS, float* __restrict__ AD,
    int N)
{
    __shared__ float Wlds[K * M];
    __shared__ float Xbuf[4][K];

    for (int i = threadIdx.x; i < K * M; i += 256) Wlds[i] = W[i];
    __syncthreads();

    const int wave = threadIdx.x >> 6;
    const int lane = threadIdx.x & 63;
    const float asv = (lane < M) ? a_s[lane] : 0.0f;
    const float adv = (lane < M) ? a_d[lane] : 0.0f;

    const int rows_per_step = gridDim.x * 4;
    for (int r0 = blockIdx.x * 4; r0 < N; r0 += rows_per_step) {
        const int r = r0 + wave;  // N % 4 == 0
        const float* xr = X + (long)r * K;
        #pragma unroll
        for (int j = lane; j < K; j += 64) {
            float v = xr[j];
            if (RELU_BIAS) { v += bias_in[j]; v = v > 0.0f ? v : 0.0f; }
            Xbuf[wave][j] = v;
        }
        __syncthreads();

        float acc = 0.0f;
        if (lane < M) {
            const float4* xb4 = (const float4*)Xbuf[wave];
            #pragma unroll 4
            for (int k4 = 0; k4 < K / 4; ++k4) {
                float4 xv = xb4[k4];
                acc = fmaf(xv.x, Wlds[(k4 * 4 + 0) * M + lane], acc);
                acc = fmaf(xv.y, Wlds[(k4 * 4 + 1) * M + lane], acc);
                acc = fmaf(xv.z, Wlds[(k4 * 4 + 2) * M + lane], acc);
                acc = fmaf(xv.w, Wlds[(k4 * 4 + 3) * M + lane], acc);
            }
            H[(long)r * M + lane] = acc;
        }
        float vs = acc * asv, vd = acc * adv;
        #pragma unroll
        for (int o = 32; o >= 1; o >>= 1) {
            vs += __shfl_xor(vs, o);
            vd += __shfl_xor(vd, o);
        }
        if (lane == 0) { AS[r] = vs; AD[r] = vd; }
        __syncthreads();
    }
}

// ===== fused softmax + aggregation over CSR: one wave per dst node =====
template <int M>  // feature width: 64 (layer1) or 32 (layer2)
__global__ __launch_bounds__(256) void agg_csr_k(
    const int* __restrict__ rowptr, const int* __restrict__ csr_src,
    const float* __restrict__ as_, const float* __restrict__ ad_,
    const float* __restrict__ H, float* __restrict__ OUT, int N)
{
    __shared__ float lw[4][64];
    __shared__ int   ls[4][64];
    const int wave = threadIdx.x >> 6;
    const int lane = threadIdx.x & 63;
    const int d = blockIdx.x * 4 + wave;
    if (d >= N) return;
    const int r0 = rowptr[d];
    const int deg = rowptr[d + 1] - r0;
    const float adv = ad_[d];

    const int f  = lane & (M - 1);
    const int eh = (M == 64) ? 0 : (lane >> 5);

    float m = NINF, den = 0.0f, acc = 0.0f;
    for (int base = 0; base < deg; base += 64) {
        int j = base + lane;
        int s = 0;
        float e = NINF;
        if (j < deg) {
            s = csr_src[r0 + j];
            e = as_[s] + adv;
            e = e > 0.0f ? e : NEG_SLOPE * e;
        }
        float cm = e;
        #pragma unroll
        for (int o = 32; o; o >>= 1) cm = fmaxf(cm, __shfl_xor(cm, o));
        if (cm > m) {
            float sc = __expf(m - cm);
            acc *= sc; den *= sc; m = cm;
        }
        float w = __expf(e - m);
        float ws = w;
        #pragma unroll
        for (int o = 32; o; o >>= 1) ws += __shfl_xor(ws, o);
        den += ws;
        lw[wave][lane] = w;
        ls[wave][lane] = s;
        int cnt = min(64, deg - base);
        if (M == 64) {
            #pragma unroll 4
            for (int jj = 0; jj < cnt; ++jj) {
                float wj = lw[wave][jj];
                int   sj = ls[wave][jj];
                acc = fmaf(wj, H[(long)sj * 64 + lane], acc);
            }
        } else {
            #pragma unroll 4
            for (int jj = 0; jj < cnt; jj += 2) {
                int je = jj + eh;
                float wj = (je < cnt) ? lw[wave][je] : 0.0f;
                int   sj = (je < cnt) ? ls[wave][je] : 0;
                acc = fmaf(wj, H[(long)sj * 32 + f], acc);
            }
        }
    }
    if (M == 32) acc += __shfl_xor(acc, 32);
    float r = acc / den;
    if (M == 64) OUT[(long)d * 64 + lane] = r;
    else if (lane < 32) OUT[(long)d * 32 + lane] = r;
}

// ---------- final FC: out[n] = relu(H2[n]+b2) . Wfc + bfc ----------
__global__ __launch_bounds__(256) void fc_out_k(
    const float* __restrict__ H2, const float* __restrict__ b2,
    const float* __restrict__ Wfc, const float* __restrict__ bfc,
    float* __restrict__ out, int N)
{
    int t = blockIdx.x * 256 + threadIdx.x;
    int n = t >> 5;
    int fidx = t & 31;
    if (n >= N) return;
    float v = H2[(long)n * 32 + fidx] + b2[fidx];
    v = v > 0.0f ? v : 0.0f;
    v *= Wfc[fidx];
    #pragma unroll
    for (int o = 16; o >= 1; o >>= 1) v += __shfl_xor(v, o, 32);
    if (fidx == 0) out[n] = v + bfc[0];
}

extern "C" void kernel_launch(void* const* d_in, const int* in_sizes, int n_in,
                              void* d_out, int out_size, void* d_ws, size_t ws_size,
                              hipStream_t stream) {
    const float* x      = (const float*)d_in[0];
    const int*   eidx   = (const int*)d_in[1];
    const float* W1     = (const float*)d_in[2];
    const float* a_src1 = (const float*)d_in[3];
    const float* a_dst1 = (const float*)d_in[4];
    const float* b1     = (const float*)d_in[5];
    const float* W2     = (const float*)d_in[6];
    const float* a_src2 = (const float*)d_in[7];
    const float* a_dst2 = (const float*)d_in[8];
    const float* b2     = (const float*)d_in[9];
    const float* Wfc    = (const float*)d_in[10];
    const float* bfc    = (const float*)d_in[11];
    float* out = (float*)d_out;

    const int N = in_sizes[0] / 256;       // 100000
    const int E = in_sizes[1] / 2;         // 1600000
    const int Etot = E + N;                // 1700000
    const int* esrc = eidx;
    const int* edst = eidx + E;

    // ---- workspace layout (4B units) ----
    int* rowptr   = (int*)d_ws;                      // N+1 (also hist counters)
    int* woff     = rowptr + (N + 1);                // N
    int* partials = woff + N;                        // 128
    int* csr      = partials + 128;                  // Etot
    float* as1  = (float*)(csr + Etot);              // N
    float* ad1  = as1 + N;                           // N
    float* as2  = ad1 + N;                           // N
    float* ad2  = as2 + N;                           // N
    float* A    = ad2 + N;                           // 64N
    float* B    = A + (long)N * 64;                  // 64N
    float* h1    = A;
    float* h1out = B;
    float* h2    = A;                                // reuse: h1 dead after agg1
    float* h2out = A + (long)N * 32;

    hipMemsetAsync(rowptr, 0, (size_t)(N + 1) * 4, stream);

    // ---- CSR build ----
    {
        int blocks = (Etot + 255) / 256;
        int nb = (N + 1023) / 1024;  // 98
        hist_k<<<blocks, 256, 0, stream>>>(edst, E, Etot, rowptr);
        scan_partial_k<<<nb, 256, 0, stream>>>(rowptr, N, partials);
        scan_partials_scan_k<<<1, 128, 0, stream>>>(partials, nb);
        scan_final_k<<<nb, 256, 0, stream>>>(rowptr, woff, partials, N, Etot);
        scatter_k<<<blocks, 256, 0, stream>>>(esrc, edst, E, Etot, woff, csr);
    }

    const int aggBlocks = (N + 3) / 4;

    // ---- layer 1 ----
    gemm_alpha<256, 64, false><<<1024, 256, 0, stream>>>(
        x, W1, a_src1, a_dst1, nullptr, h1, as1, ad1, N);
    agg_csr_k<64><<<aggBlocks, 256, 0, stream>>>(
        rowptr, csr, as1, ad1, h1, h1out, N);

    // ---- layer 2 ----
    gemm_alpha<64, 32, true><<<1024, 256, 0, stream>>>(
        h1out, W2, a_src2, a_dst2, b1, h2, as2, ad2, N);
    agg_csr_k<32><<<aggBlocks, 256, 0, stream>>>(
        rowptr, csr, as2, ad2, h2, h2out, N);

    // ---- final FC ----
    {
        int blocks = (int)(((long)N * 32 + 255) / 256);
        fc_out_k<<<blocks, 256, 0, stream>>>(h2out, b2, Wfc, bfc, out, N);
    }
}

// Round 4
// 538.629 us; speedup vs baseline: 2.3321x; 1.3463x over previous
//
#include <hip/hip_runtime.h>
#include <hip/hip_bf16.h>

#define NEG_SLOPE 0.2f
#define NINF (-1e30f)

typedef __attribute__((ext_vector_type(8))) short s8v;
typedef __attribute__((ext_vector_type(4))) float f4v;

__device__ __forceinline__ unsigned short f2bf(float f) {
    unsigned u = __float_as_uint(f);
    u = (u + 0x7fffu + ((u >> 16) & 1u)) >> 16;
    return (unsigned short)u;
}
__device__ __forceinline__ float bf2f(unsigned short h) {
    return __uint_as_float(((unsigned)h) << 16);
}

// ================= CSR build (graph shared by both layers) =================

__global__ __launch_bounds__(256) void hist_k(
    const int* __restrict__ edst, int E, int Etot, int* __restrict__ cnt)
{
    int i = blockIdx.x * 256 + threadIdx.x;
    if (i >= Etot) return;
    int d = (i < E) ? edst[i] : (i - E);
    atomicAdd(cnt + d, 1);
}

__global__ __launch_bounds__(256) void scan_partial_k(
    const int* __restrict__ cnt, int N, int* __restrict__ partials)
{
    __shared__ int red[256];
    const int t = threadIdx.x;
    const int base = blockIdx.x * 1024 + t * 4;
    int sum = 0;
    #pragma unroll
    for (int k = 0; k < 4; ++k) {
        int i = base + k;
        if (i < N) sum += cnt[i];
    }
    red[t] = sum;
    __syncthreads();
    #pragma unroll
    for (int o = 128; o; o >>= 1) {
        if (t < o) red[t] += red[t + o];
        __syncthreads();
    }
    if (t == 0) partials[blockIdx.x] = red[0];
}

__global__ __launch_bounds__(128) void scan_partials_scan_k(
    int* __restrict__ partials, int nb)
{
    __shared__ int sh[128];
    const int t = threadIdx.x;
    int v = (t < nb) ? partials[t] : 0;
    sh[t] = v;
    __syncthreads();
    #pragma unroll
    for (int o = 1; o < 128; o <<= 1) {
        int u = (t >= o) ? sh[t - o] : 0;
        __syncthreads();
        sh[t] += u;
        __syncthreads();
    }
    if (t < nb) partials[t] = sh[t] - v;  // exclusive
}

__global__ __launch_bounds__(256) void scan_final_k(
    int* __restrict__ cnt, int* __restrict__ woff,
    const int* __restrict__ partials, int N, int Etot)
{
    __shared__ int sh[256];
    const int t = threadIdx.x;
    const int base = blockIdx.x * 1024 + t * 4;
    int v[4];
    int sum = 0;
    #pragma unroll
    for (int k = 0; k < 4; ++k) {
        int i = base + k;
        v[k] = (i < N) ? cnt[i] : 0;
        sum += v[k];
    }
    sh[t] = sum;
    __syncthreads();
    #pragma unroll
    for (int o = 1; o < 256; o <<= 1) {
        int u = (t >= o) ? sh[t - o] : 0;
        __syncthreads();
        sh[t] += u;
        __syncthreads();
    }
    int run = sh[t] - sum + partials[blockIdx.x];
    #pragma unroll
    for (int k = 0; k < 4; ++k) {
        int i = base + k;
        if (i < N) { cnt[i] = run; woff[i] = run; }
        run += v[k];
    }
    if (blockIdx.x == 0 && t == 0) cnt[N] = Etot;
}

__global__ __launch_bounds__(256) void scatter_k(
    const int* __restrict__ esrc, const int* __restrict__ edst, int E, int Etot,
    int* __restrict__ woff, int* __restrict__ csr_src)
{
    int i = blockIdx.x * 256 + threadIdx.x;
    if (i >= Etot) return;
    int d = (i < E) ? edst[i] : (i - E);
    int s = (i < E) ? esrc[i] : (i - E);
    int pos = atomicAdd(woff + d, 1);
    csr_src[pos] = s;
}

// ===== prep: transpose + split W into bf16 hi/lo =====
__global__ __launch_bounds__(256) void prep_w_k(
    const float* __restrict__ W1, const float* __restrict__ W2,
    short* __restrict__ Wt1h, short* __restrict__ Wt1l,
    short* __restrict__ Wt2h, short* __restrict__ Wt2l)
{
    int t = blockIdx.x * 256 + threadIdx.x;
    if (t < 256 * 64) {
        int k = t >> 6, c = t & 63;
        float v = W1[t];
        unsigned short h = f2bf(v);
        unsigned short l = f2bf(v - bf2f(h));
        Wt1h[c * 256 + k] = (short)h;
        Wt1l[c * 256 + k] = (short)l;
    } else if (t < 256 * 64 + 64 * 32) {
        int e = t - 256 * 64;
        int k = e >> 5, c = e & 31;
        float v = W2[e];
        unsigned short h = f2bf(v);
        unsigned short l = f2bf(v - bf2f(h));
        Wt2h[c * 64 + k] = (short)h;
        Wt2l[c * 64 + k] = (short)l;
    }
}

// ===== MFMA GEMM (split-bf16): Hb = bf16(f(X) @ W), AS/AD fused =====
// f(X) = relu(X + bias_in) if RELU_BIAS. 64 rows/block, wave w -> rows w*16..+15.
template <int K, int M, bool RELU_BIAS>
__global__ __launch_bounds__(256) void gemm_mfma_k(
    const float* __restrict__ X,
    const short* __restrict__ Wth, const short* __restrict__ Wtl,
    const float* __restrict__ a_s, const float* __restrict__ a_d,
    const float* __restrict__ bias_in,
    unsigned short* __restrict__ Hb, float* __restrict__ AS, float* __restrict__ AD,
    int N)
{
    constexpr int NT = M / 16;   // col tiles
    constexpr int KS = K / 32;   // k steps
    __shared__ short Xhi[64][40];
    __shared__ short Xlo[64][40];

    const int wave = threadIdx.x >> 6;
    const int lane = threadIdx.x & 63;
    const int lc = lane & 15;
    const int k8 = (lane >> 4) * 8;
    const int rb = blockIdx.x * 64;

    const int trow = threadIdx.x >> 2;        // 0..63
    const int tseg = (threadIdx.x & 3) * 8;   // 0,8,16,24

    f4v acc[NT];
    #pragma unroll
    for (int c = 0; c < NT; ++c) acc[c] = (f4v){0.f, 0.f, 0.f, 0.f};

    for (int ks = 0; ks < KS; ++ks) {
        // ---- stage 64 rows x 32 k (fp32 -> bf16 hi/lo) ----
        int gr = rb + trow;
        float v[8];
        if (gr < N) {
            const float* src = X + (long)gr * K + ks * 32 + tseg;
            float4 v0 = *(const float4*)(src);
            float4 v1 = *(const float4*)(src + 4);
            v[0] = v0.x; v[1] = v0.y; v[2] = v0.z; v[3] = v0.w;
            v[4] = v1.x; v[5] = v1.y; v[6] = v1.z; v[7] = v1.w;
        } else {
            #pragma unroll
            for (int j = 0; j < 8; ++j) v[j] = 0.f;
        }
        if (RELU_BIAS) {
            #pragma unroll
            for (int j = 0; j < 8; ++j) {
                float w = v[j] + bias_in[ks * 32 + tseg + j];
                v[j] = w > 0.f ? w : 0.f;
            }
        }
        s8v hv, lv;
        #pragma unroll
        for (int j = 0; j < 8; ++j) {
            unsigned short h = f2bf(v[j]);
            hv[j] = (short)h;
            lv[j] = (short)f2bf(v[j] - bf2f(h));
        }
        *(s8v*)&Xhi[trow][tseg] = hv;
        *(s8v*)&Xlo[trow][tseg] = lv;
        __syncthreads();

        // ---- fragments + 3-product split MFMA ----
        const int arow = wave * 16 + lc;
        s8v ah = *(const s8v*)&Xhi[arow][k8];
        s8v al = *(const s8v*)&Xlo[arow][k8];
        #pragma unroll
        for (int c = 0; c < NT; ++c) {
            const long wo = (long)(c * 16 + lc) * K + ks * 32 + k8;
            s8v bh = *(const s8v*)(Wth + wo);
            s8v bl = *(const s8v*)(Wtl + wo);
            acc[c] = __builtin_amdgcn_mfma_f32_16x16x32_bf16(ah, bh, acc[c], 0, 0, 0);
            acc[c] = __builtin_amdgcn_mfma_f32_16x16x32_bf16(al, bh, acc[c], 0, 0, 0);
            acc[c] = __builtin_amdgcn_mfma_f32_16x16x32_bf16(ah, bl, acc[c], 0, 0, 0);
        }
        __syncthreads();
    }

    // ---- epilogue: store bf16 H, fused alpha dots ----
    float ps[4] = {0.f, 0.f, 0.f, 0.f}, pd[4] = {0.f, 0.f, 0.f, 0.f};
    #pragma unroll
    for (int c = 0; c < NT; ++c) {
        float asv = a_s[c * 16 + lc];
        float adv = a_d[c * 16 + lc];
        #pragma unroll
        for (int j = 0; j < 4; ++j) {
            float hval = acc[c][j];
            int grow = rb + wave * 16 + (lane >> 4) * 4 + j;
            if (grow < N) Hb[(long)grow * M + c * 16 + lc] = f2bf(hval);
            ps[j] = fmaf(hval, asv, ps[j]);
            pd[j] = fmaf(hval, adv, pd[j]);
        }
    }
    #pragma unroll
    for (int j = 0; j < 4; ++j) {
        #pragma unroll
        for (int o = 8; o >= 1; o >>= 1) {
            ps[j] += __shfl_xor(ps[j], o);
            pd[j] += __shfl_xor(pd[j], o);
        }
    }
    if (lc == 0) {
        #pragma unroll
        for (int j = 0; j < 4; ++j) {
            int grow = rb + wave * 16 + (lane >> 4) * 4 + j;
            if (grow < N) { AS[grow] = ps[j]; AD[grow] = pd[j]; }
        }
    }
}

// ===== fused softmax + aggregation over CSR: one wave per dst node =====
// EH = 64/(M/2) edges processed per iteration; 2 features (ushort2) per lane.
template <int M>
__global__ __launch_bounds__(256) void agg_csr_k(
    const int* __restrict__ rowptr, const int* __restrict__ csr_src,
    const float* __restrict__ as_, const float* __restrict__ ad_,
    const unsigned short* __restrict__ H, float* __restrict__ OUT, int N)
{
    constexpr int LP = M / 2;      // lanes per edge
    constexpr int EH = 64 / LP;    // edges per iteration
    __shared__ float lw[4][64];
    __shared__ int   ls[4][64];
    const int wave = threadIdx.x >> 6;
    const int lane = threadIdx.x & 63;
    const int d = blockIdx.x * 4 + wave;
    if (d >= N) return;
    const int r0 = rowptr[d];
    const int deg = rowptr[d + 1] - r0;
    const float adv = ad_[d];

    const int f2 = (lane % LP) * 2;
    const int eh = lane / LP;

    float m = NINF, den = 0.0f, acc0 = 0.0f, acc1 = 0.0f;
    for (int base = 0; base < deg; base += 64) {
        int j = base + lane;
        int s = 0;
        float e = NINF;
        if (j < deg) {
            s = csr_src[r0 + j];
            e = as_[s] + adv;
            e = e > 0.0f ? e : NEG_SLOPE * e;
        }
        float cm = e;
        #pragma unroll
        for (int o = 32; o; o >>= 1) cm = fmaxf(cm, __shfl_xor(cm, o));
        if (cm > m) {
            float sc = __expf(m - cm);  // m=-inf -> 0 (zeroes stale state)
            acc0 *= sc; acc1 *= sc; den *= sc; m = cm;
        }
        float w = __expf(e - m);
        float wsum = w;
        #pragma unroll
        for (int o = 32; o; o >>= 1) wsum += __shfl_xor(wsum, o);
        den += wsum;
        lw[wave][lane] = w;
        ls[wave][lane] = s;
        int cnt = min(64, deg - base);
        #pragma unroll 4
        for (int jj = 0; jj < cnt; jj += EH) {
            int je = jj + eh;
            float wj = (je < cnt) ? lw[wave][je] : 0.0f;
            int   sj = (je < cnt) ? ls[wave][je] : 0;
            unsigned hv = *(const unsigned*)&H[(long)sj * M + f2];
            acc0 = fmaf(wj, bf2f((unsigned short)(hv & 0xffffu)), acc0);
            acc1 = fmaf(wj, bf2f((unsigned short)(hv >> 16)), acc1);
        }
    }
    #pragma unroll
    for (int o = LP; o < 64; o <<= 1) {
        acc0 += __shfl_xor(acc0, o);
        acc1 += __shfl_xor(acc1, o);
    }
    if (lane < LP) {
        float inv = 1.0f / den;
        *(float2*)&OUT[(long)d * M + f2] = make_float2(acc0 * inv, acc1 * inv);
    }
}

// ---------- final FC: out[n] = relu(H2[n]+b2) . Wfc + bfc ----------
__global__ __launch_bounds__(256) void fc_out_k(
    const float* __restrict__ H2, const float* __restrict__ b2,
    const float* __restrict__ Wfc, const float* __restrict__ bfc,
    float* __restrict__ out, int N)
{
    int t = blockIdx.x * 256 + threadIdx.x;
    int n = t >> 5;
    int fidx = t & 31;
    if (n >= N) return;
    float v = H2[(long)n * 32 + fidx] + b2[fidx];
    v = v > 0.0f ? v : 0.0f;
    v *= Wfc[fidx];
    #pragma unroll
    for (int o = 16; o >= 1; o >>= 1) v += __shfl_xor(v, o, 32);
    if (fidx == 0) out[n] = v + bfc[0];
}

extern "C" void kernel_launch(void* const* d_in, const int* in_sizes, int n_in,
                              void* d_out, int out_size, void* d_ws, size_t ws_size,
                              hipStream_t stream) {
    const float* x      = (const float*)d_in[0];
    const int*   eidx   = (const int*)d_in[1];
    const float* W1     = (const float*)d_in[2];
    const float* a_src1 = (const float*)d_in[3];
    const float* a_dst1 = (const float*)d_in[4];
    const float* b1     = (const float*)d_in[5];
    const float* W2     = (const float*)d_in[6];
    const float* a_src2 = (const float*)d_in[7];
    const float* a_dst2 = (const float*)d_in[8];
    const float* b2     = (const float*)d_in[9];
    const float* Wfc    = (const float*)d_in[10];
    const float* bfc    = (const float*)d_in[11];
    float* out = (float*)d_out;

    const int N = in_sizes[0] / 256;       // 100000
    const int E = in_sizes[1] / 2;         // 1600000
    const int Etot = E + N;                // 1700000
    const int* esrc = eidx;
    const int* edst = eidx + E;

    // ---- workspace bump allocator (256B-aligned regions) ----
    char* cur = (char*)d_ws;
    auto alloc = [&](size_t bytes) -> void* {
        void* r = (void*)cur;
        cur += (bytes + 255) & ~(size_t)255;
        return r;
    };
    int* rowptr   = (int*)alloc((size_t)(N + 1) * 4);
    int* woff     = (int*)alloc((size_t)N * 4);
    int* partials = (int*)alloc(512);
    int* csr      = (int*)alloc((size_t)Etot * 4);
    float* as1    = (float*)alloc((size_t)N * 4);
    float* ad1    = (float*)alloc((size_t)N * 4);
    float* as2    = (float*)alloc((size_t)N * 4);
    float* ad2    = (float*)alloc((size_t)N * 4);
    short* Wt1h   = (short*)alloc(16384 * 2);
    short* Wt1l   = (short*)alloc(16384 * 2);
    short* Wt2h   = (short*)alloc(2048 * 2);
    short* Wt2l   = (short*)alloc(2048 * 2);
    unsigned short* h1b = (unsigned short*)alloc((size_t)N * 64 * 2);
    unsigned short* h2b = (unsigned short*)alloc((size_t)N * 32 * 2);
    float* h1out  = (float*)alloc((size_t)N * 64 * 4);
    float* h2out  = (float*)alloc((size_t)N * 32 * 4);

    hipMemsetAsync(rowptr, 0, (size_t)(N + 1) * 4, stream);

    // ---- weight prep + CSR build ----
    prep_w_k<<<72, 256, 0, stream>>>(W1, W2, Wt1h, Wt1l, Wt2h, Wt2l);
    {
        int blocks = (Etot + 255) / 256;
        int nb = (N + 1023) / 1024;  // 98
        hist_k<<<blocks, 256, 0, stream>>>(edst, E, Etot, rowptr);
        scan_partial_k<<<nb, 256, 0, stream>>>(rowptr, N, partials);
        scan_partials_scan_k<<<1, 128, 0, stream>>>(partials, nb);
        scan_final_k<<<nb, 256, 0, stream>>>(rowptr, woff, partials, N, Etot);
        scatter_k<<<blocks, 256, 0, stream>>>(esrc, edst, E, Etot, woff, csr);
    }

    const int gemmBlocks = (N + 63) / 64;   // 1563
    const int aggBlocks  = (N + 3) / 4;

    // ---- layer 1 ----
    gemm_mfma_k<256, 64, false><<<gemmBlocks, 256, 0, stream>>>(
        x, Wt1h, Wt1l, a_src1, a_dst1, nullptr, h1b, as1, ad1, N);
    agg_csr_k<64><<<aggBlocks, 256, 0, stream>>>(
        rowptr, csr, as1, ad1, h1b, h1out, N);

    // ---- layer 2 (bias1 + relu fused into staging) ----
    gemm_mfma_k<64, 32, true><<<gemmBlocks, 256, 0, stream>>>(
        h1out, Wt2h, Wt2l, a_src2, a_dst2, b1, h2b, as2, ad2, N);
    agg_csr_k<32><<<aggBlocks, 256, 0, stream>>>(
        rowptr, csr, as2, ad2, h2b, h2out, N);

    // ---- final FC ----
    {
        int blocks = (int)(((long)N * 32 + 255) / 256);
        fc_out_k<<<blocks, 256, 0, stream>>>(h2out, b2, Wfc, bfc, out, N);
    }
}